// Round 12
// baseline (4663.973 us; speedup 1.0000x reference)
//
#include <hip/hip_runtime.h>

typedef _Float16 half8 __attribute__((ext_vector_type(8)));
typedef _Float16 half4 __attribute__((ext_vector_type(4)));
typedef float floatx4 __attribute__((ext_vector_type(4)));

static constexpr int BATCH = 1024;
static constexpr int NIN   = 512;    // in_features
static constexpr int MOUT  = 1024;   // out_features
static constexpr float LAMBD = 0.2f;
static constexpr float TOLF  = 1e-4f;
static constexpr int MAX_ITERS = 100;
static constexpr int MM = BATCH * MOUT;   // 1M elements

// Fragment-swizzled layout for 16x16x32 MFMA operands (A: rows, B: cols), f16:
//   flat = ((tile16*32 + kchunk32)*64 + lane)*8 + elem
//   lane = (idx&15) | (((k>>3)&3)<<4), elem = k&7
// One (tile16, k32) fragment = 1 KB contiguous chunk in lane order.
__device__ __forceinline__ size_t swz(int idx, int k) {
    return ((((size_t)(idx >> 4) * 32 + (k >> 5)) * 64 +
             ((idx & 15) | (((k >> 3) & 3) << 4))) << 3) + (k & 7);
}

__device__ __forceinline__ float shrinkf(float t) {
    float a = fabsf(t) - LAMBD;
    return a > 0.f ? copysignf(a, t) : 0.f;
}

// ---------------------------------------------------------------------------
// zero-init: enc, dec, swizzled enc halves
// ---------------------------------------------------------------------------
__global__ __launch_bounds__(256) void zero_init(float* enc, float* dec,
                                                 float* ench_f, float* encl_f) {
    int i = blockIdx.x * 256 + threadIdx.x;
    if (i < MM) enc[i] = 0.f;
    if (i < MM / 2) { dec[i] = 0.f; ench_f[i] = 0.f; encl_f[i] = 0.f; }
}

// ---------------------------------------------------------------------------
// Th/Tl = B-fragment-swizzled split-f16 of Minv (col=n in 1024, k in 1024).
// ---------------------------------------------------------------------------
__global__ __launch_bounds__(256) void split_minv(const float* __restrict__ Minv,
                                                  _Float16* __restrict__ Th,
                                                  _Float16* __restrict__ Tl) {
    int g = blockIdx.x * 256 + threadIdx.x;   // 131072 threads
    int n = g & 1023, k0 = (g >> 10) << 3;
    half8 h, l;
    #pragma unroll
    for (int e = 0; e < 8; ++e) {
        float val = Minv[(size_t)(k0 + e) * MOUT + n];
        _Float16 hh = (_Float16)val;
        h[e] = hh;
        l[e] = (_Float16)(val - (float)hh);
    }
    size_t off = swz(n, k0);
    *(half8*)&Th[off] = h;
    *(half8*)&Tl[off] = l;
}

// ---------------------------------------------------------------------------
// wsh/wsl = B-fragment-swizzled split-f16 of weight (col=n in 512, k in 1024).
// ---------------------------------------------------------------------------
__global__ __launch_bounds__(256) void split_w(const float* __restrict__ w,
                                               _Float16* __restrict__ wsh,
                                               _Float16* __restrict__ wsl) {
    int g = blockIdx.x * 256 + threadIdx.x;   // 65536 threads
    int n = g & 511, k0 = (g >> 9) << 3;
    half8 h, l;
    #pragma unroll
    for (int e = 0; e < 8; ++e) {
        float val = w[(size_t)(k0 + e) * NIN + n];
        _Float16 hh = (_Float16)val;
        h[e] = hh;
        l[e] = (_Float16)(val - (float)hh);
    }
    size_t off = swz(n, k0);
    *(half8*)&wsh[off] = h;
    *(half8*)&wsl[off] = l;
}

// ---------------------------------------------------------------------------
// adb = x @ w^T (fp32, once). Epilogue emits beff0 = adb as A-swizzled h/l.
// ---------------------------------------------------------------------------
__global__ __launch_bounds__(256) void gemm_adb(const float* __restrict__ x,
                                                const float* __restrict__ w,
                                                float* __restrict__ adb,
                                                _Float16* __restrict__ bh,
                                                _Float16* __restrict__ bl) {
    __shared__ float As[16][68];
    __shared__ float Bs[16][68];
    const int tid = threadIdx.x;
    const int i0 = (blockIdx.x >> 4) * 64, j0 = (blockIdx.x & 15) * 64;
    const int tx = tid & 15, ty = tid >> 4;
    const int lr = tid >> 2, lk = (tid & 3) << 2;
    float acc[4][4] = {};
    for (int k0 = 0; k0 < NIN; k0 += 16) {
        float4 a4 = *(const float4*)&x[(i0 + lr) * NIN + k0 + lk];
        As[lk + 0][lr] = a4.x; As[lk + 1][lr] = a4.y;
        As[lk + 2][lr] = a4.z; As[lk + 3][lr] = a4.w;
        float4 b4 = *(const float4*)&w[(j0 + lr) * NIN + k0 + lk];
        Bs[lk + 0][lr] = b4.x; Bs[lk + 1][lr] = b4.y;
        Bs[lk + 2][lr] = b4.z; Bs[lk + 3][lr] = b4.w;
        __syncthreads();
        #pragma unroll
        for (int kk = 0; kk < 16; ++kk) {
            float4 a_ = *(const float4*)&As[kk][ty << 2];
            float4 b_ = *(const float4*)&Bs[kk][tx << 2];
            #pragma unroll
            for (int r = 0; r < 4; ++r) {
                float av = r == 0 ? a_.x : r == 1 ? a_.y : r == 2 ? a_.z : a_.w;
                acc[r][0] = fmaf(av, b_.x, acc[r][0]);
                acc[r][1] = fmaf(av, b_.y, acc[r][1]);
                acc[r][2] = fmaf(av, b_.z, acc[r][2]);
                acc[r][3] = fmaf(av, b_.w, acc[r][3]);
            }
        }
        __syncthreads();
    }
    const int k4 = j0 + (tx << 2);
    #pragma unroll
    for (int r = 0; r < 4; ++r) {
        const int row = i0 + (ty << 2) + r;
        *(float4*)&adb[(size_t)row * MOUT + k4] =
            make_float4(acc[r][0], acc[r][1], acc[r][2], acc[r][3]);
        half4 h, l;
        #pragma unroll
        for (int e = 0; e < 4; ++e) {
            _Float16 hh = (_Float16)acc[r][e];
            h[e] = hh;
            l[e] = (_Float16)(acc[r][e] - (float)hh);
        }
        size_t off = swz(row, k4);
        *(half4*)&bh[off] = h;
        *(half4*)&bl[off] = l;
    }
}

// ---------------------------------------------------------------------------
// Fully-fused ADMM: ONE dispatch for all 100 iterations. 64 blocks x 1024 thr
// (16 waves, 1 block/CU). Block owns 16 rows; per iteration computes its full
// 16x1024 xk tile (K=1024) and the row updates — rows are independent across
// blocks, so NO inter-block communication, only __syncthreads.
//   A (beff split h/l) lives in LDS (64 KB), rewritten in place by updates.
//   B (Th/Tl, 4 MB constant) streams from per-XCD L2 (read-only, replicated).
//   xk exchanged via a second LDS buffer (row stride 1028 -> 2-way banks).
//   t-state in VGPRs: wave w owns row w, lane owns cols {lane + 64q}.
//   Block exits when all 16 rows frozen. Frozen rows stop updating (ref sem).
// ---------------------------------------------------------------------------
__global__ __launch_bounds__(1024, 1)
void admm_fused(const _Float16* __restrict__ bh0, const _Float16* __restrict__ bl0,
                const _Float16* __restrict__ Th, const _Float16* __restrict__ Tl,
                const float* __restrict__ adb, float* __restrict__ enc,
                _Float16* __restrict__ ench, _Float16* __restrict__ encl) {
    __shared__ _Float16 Ash[2][32 * 512];   // 64 KB: [hl][kc<<9 | lanePos<<3 | e]
    __shared__ float Xk[16 * 1028];         // 64.25 KB, padded row stride
    __shared__ int scnt;

    const int bid = blockIdx.x;             // row-tile 0..63
    const int tid = threadIdx.x, lane = tid & 63, wv = tid >> 6;
    const int row = (bid << 4) + wv;        // this wave's row

    // ---- stage initial beff = adb (swizzled split) into LDS A: 64 x 1 KB
    #pragma unroll
    for (int i = 0; i < 4; ++i) {
        const int ch = (wv << 2) + i;       // 0..63
        const int hl = ch >> 5, kc = ch & 31;
        const _Float16* src = (hl ? bl0 : bh0) +
            ((((size_t)bid * 32 + kc) << 9) + ((size_t)lane << 3));
        __builtin_amdgcn_global_load_lds(
            (const __attribute__((address_space(1))) void*)src,
            (__attribute__((address_space(3))) void*)&Ash[hl][kc << 9],
            16, 0, 0);
    }
    if (tid == 0) scnt = 0;

    // ---- per-lane state: cols {lane + 64q}
    float tR[16], aR[16];
    const float* adbp = adb + ((size_t)row << 10) + lane;
    #pragma unroll
    for (int q = 0; q < 16; ++q) { tR[q] = 0.f; aR[q] = adbp[q << 6]; }

    const int ct0 = wv << 2;                // wave's 4 col-tiles
    const _Float16* pBh = Th + ((((size_t)ct0 * 32) * 64 + (size_t)lane) << 3);
    const _Float16* pBl = Tl + ((((size_t)ct0 * 32) * 64 + (size_t)lane) << 3);

    bool mydone = false;
    __syncthreads();                        // staging drained

    for (int iter = 0; iter < MAX_ITERS; ++iter) {
        // ======== GEMM: rows 0..15 x cols [64*wv, 64*wv+64), K = 1024 ========
        floatx4 acc[4] = {};
        #pragma unroll 2
        for (int kc = 0; kc < 32; ++kc) {
            half8 ah = *(const half8*)&Ash[0][(kc << 9) + (lane << 3)];
            half8 al = *(const half8*)&Ash[1][(kc << 9) + (lane << 3)];
            #pragma unroll
            for (int j = 0; j < 4; ++j) {
                half8 fh = *(const half8*)(pBh + ((size_t)((j << 5) + kc) << 9));
                half8 fl = *(const half8*)(pBl + ((size_t)((j << 5) + kc) << 9));
                acc[j] = __builtin_amdgcn_mfma_f32_16x16x32_f16(ah, fl, acc[j], 0, 0, 0);
                acc[j] = __builtin_amdgcn_mfma_f32_16x16x32_f16(al, fh, acc[j], 0, 0, 0);
                acc[j] = __builtin_amdgcn_mfma_f32_16x16x32_f16(ah, fh, acc[j], 0, 0, 0);
            }
        }
        // scatter C to Xk: col = lane&15, row = (lane>>4)*4 + r  [m89 verified]
        {
            const int ccol = lane & 15, crow = (lane >> 4) << 2;
            #pragma unroll
            for (int j = 0; j < 4; ++j) {
                const int cb = ((ct0 + j) << 4) + ccol;
                #pragma unroll
                for (int r = 0; r < 4; ++r)
                    Xk[(crow + r) * 1028 + cb] = acc[j][r];
            }
        }
        __syncthreads();                     // xk complete

        // ======== update row wv (t-trick; ref-order arithmetic) ========
        if (!mydone) {
            float dx2 = 0.f, x2 = 0.f;
            float vnv[16], tno[16];
            #pragma unroll
            for (int q = 0; q < 16; ++q) {
                float kx = Xk[wv * 1028 + lane + (q << 6)];
                float tp = tR[q];
                float vprev = shrinkf(tp);
                float uu = tp - vprev;       // u_prev (bitwise = stored u)
                float tn = kx + uu;          // xk + u (ref order)
                float vv = shrinkf(tn);
                float d = vv - vprev;
                dx2 += d * d;
                x2 += vv * vv;
                vnv[q] = vv;
                tno[q] = tn;
            }
            #pragma unroll
            for (int off = 32; off; off >>= 1) {
                dx2 += __shfl_xor(dx2, off);
                x2  += __shfl_xor(x2, off);
            }
            if (dx2 < TOLF * TOLF * x2) {    // x2==0 -> false (NaN semantics)
                // freeze: emit enc row + swizzled split enc for the dec GEMM
                #pragma unroll
                for (int q = 0; q < 16; ++q) {
                    const int col = lane + (q << 6);
                    enc[((size_t)row << 10) + col] = vnv[q];
                    _Float16 hh = (_Float16)vnv[q];
                    _Float16 ll = (_Float16)(vnv[q] - (float)hh);
                    const size_t off = ((((size_t)bid * 32 + (col >> 5)) << 9)) +
                        (((size_t)(wv | (((col >> 3) & 3) << 4))) << 3) + (col & 7);
                    ench[off] = hh;
                    encl[off] = ll;
                }
                mydone = true;
                if (lane == 0) atomicAdd(&scnt, 1);
            } else {
                // advance state; rewrite this row's beff into LDS A (in place)
                #pragma unroll
                for (int q = 0; q < 16; ++q) {
                    tR[q] = tno[q];
                    const int col = lane + (q << 6);
                    float un = tno[q] - vnv[q];          // u_new
                    float nb = (aR[q] + vnv[q]) - un;    // (adb + v_new) - u_new
                    _Float16 hh = (_Float16)nb;
                    _Float16 ll = (_Float16)(nb - (float)hh);
                    const int lo = ((col >> 5) << 9) +
                        ((wv | (((col >> 3) & 3) << 4)) << 3) + (col & 7);
                    Ash[0][lo] = hh;
                    Ash[1][lo] = ll;
                }
            }
        }
        __syncthreads();                     // A rewrite complete; scnt visible
        if (scnt == 16) break;               // block-local early exit
    }
}

// ---------------------------------------------------------------------------
// dec = enc @ w, split-f16 MFMA, runs ONCE. 128x128 tile, S=8 whole-partition
// A staging (64 KB), one barrier, atomicAdd epilogue (one-time cost).
// ---------------------------------------------------------------------------
__global__ __launch_bounds__(256, 2)
void mfma_dec(const _Float16* __restrict__ Ahg, const _Float16* __restrict__ Alg,
              const _Float16* __restrict__ Bhg, const _Float16* __restrict__ Blg,
              float* __restrict__ out) {
    constexpr int NSTR = NIN;              // 512
    constexpr int NT = NSTR / 128;         // 4
    const int bid = blockIdx.x;
    const int c = bid & 7, t = bid >> 3;
    const int mt = t / NT, nt = t % NT;
    const int tid = threadIdx.x, lane = tid & 63;

    __shared__ _Float16 Ash[64 * 512];     // 64 KB

    const int wv = tid >> 6;
    const int wm = (tid >> 7) & 1, wn = (tid >> 6) & 1;
    const int kf0 = c << 2;

    #pragma unroll
    for (int i = 0; i < 16; ++i) {
        const int chunk = (wv << 4) + i;
        const int rt = chunk >> 3, kc = (chunk >> 1) & 3, hl = chunk & 1;
        const _Float16* src = (hl ? Alg : Ahg) +
            ((((size_t)((mt << 3) + rt) * 32 + kf0 + kc) << 9) + ((size_t)lane << 3));
        __builtin_amdgcn_global_load_lds(
            (const __attribute__((address_space(1))) void*)src,
            (__attribute__((address_space(3))) void*)&Ash[(size_t)chunk << 9],
            16, 0, 0);
    }
    __syncthreads();

    const int ct0 = nt * 8 + (wn << 2);
    const _Float16* pBh = Bhg + ((((size_t)ct0 * 32 + kf0) * 64 + lane) << 3);
    const _Float16* pBl = Blg + ((((size_t)ct0 * 32 + kf0) * 64 + lane) << 3);

    floatx4 acc[4][4] = {};
    #pragma unroll
    for (int s = 0; s < 4; ++s) {
        half8 bhf[4], blf[4];
        #pragma unroll
        for (int j = 0; j < 4; ++j) {
            bhf[j] = *(const half8*)(pBh + ((size_t)j << 14) + ((size_t)s << 9));
            blf[j] = *(const half8*)(pBl + ((size_t)j << 14) + ((size_t)s << 9));
        }
        half8 ah[4], al[4];
        #pragma unroll
        for (int i = 0; i < 4; ++i) {
            const int rt = (wm << 2) + i;
            ah[i] = *(const half8*)&Ash[((((rt << 2) + s) << 1) << 9) + (lane << 3)];
            al[i] = *(const half8*)&Ash[(((((rt << 2) + s) << 1) + 1) << 9) + (lane << 3)];
        }
        #pragma unroll
        for (int i = 0; i < 4; ++i)
            #pragma unroll
            for (int j = 0; j < 4; ++j) {
                acc[i][j] = __builtin_amdgcn_mfma_f32_16x16x32_f16(
                    ah[i], blf[j], acc[i][j], 0, 0, 0);
                acc[i][j] = __builtin_amdgcn_mfma_f32_16x16x32_f16(
                    al[i], bhf[j], acc[i][j], 0, 0, 0);
                acc[i][j] = __builtin_amdgcn_mfma_f32_16x16x32_f16(
                    ah[i], bhf[j], acc[i][j], 0, 0, 0);
            }
    }

    const int orow = (lane >> 4) << 2;
    #pragma unroll
    for (int i = 0; i < 4; ++i) {
        const int gr = (mt << 7) + (wm << 6) + (i << 4) + orow;
        #pragma unroll
        for (int j = 0; j < 4; ++j) {
            const int gc = nt * 128 + (wn << 6) + (j << 4) + (lane & 15);
            #pragma unroll
            for (int r = 0; r < 4; ++r)
                atomicAdd(&out[(size_t)(gr + r) * NSTR + gc], acc[i][j][r]);
        }
    }
}

// ---------------------------------------------------------------------------
extern "C" void kernel_launch(void* const* d_in, const int* in_sizes, int n_in,
                              void* d_out, int out_size, void* d_ws, size_t ws_size,
                              hipStream_t stream) {
    const float* x    = (const float*)d_in[0];
    const float* w    = (const float*)d_in[1];
    const float* Minv = (const float*)d_in[2];

    float* enc = (float*)d_out;          // encoded: 1024*1024
    float* dec = enc + MM;               // decoded: 1024*512

    // ws (floats): adb MM | halves: bh0,bl0,Th,Tl,ench,encl MM each, wsh,wsl
    // MM/2 each. ~18 MB total.
    float* ws  = (float*)d_ws;
    float* adb = ws;

    _Float16* bh0  = (_Float16*)(ws + (size_t)MM);
    _Float16* bl0  = bh0 + (size_t)MM;
    _Float16* Th   = bl0 + (size_t)MM;
    _Float16* Tl   = Th + (size_t)MM;
    _Float16* ench = Tl + (size_t)MM;
    _Float16* encl = ench + (size_t)MM;
    _Float16* wsh  = encl + (size_t)MM;
    _Float16* wsl  = wsh + (size_t)(NIN * MOUT);

    zero_init<<<(MM + 255) / 256, 256, 0, stream>>>(enc, dec, (float*)ench,
                                                    (float*)encl);
    split_minv<<<512, 256, 0, stream>>>(Minv, Th, Tl);
    split_w<<<256, 256, 0, stream>>>(w, wsh, wsl);
    gemm_adb<<<256, 256, 0, stream>>>(x, w, adb, bh0, bl0);

    // the entire 100-iteration ADMM loop: ONE dispatch
    admm_fused<<<64, 1024, 0, stream>>>(bh0, bl0, Th, Tl, adb, enc, ench, encl);

    mfma_dec<<<256, 256, 0, stream>>>(ench, encl, wsh, wsl, dec);
}

// Round 13
// 2364.735 us; speedup vs baseline: 1.9723x; 1.9723x over previous
//
#include <hip/hip_runtime.h>

typedef _Float16 half8 __attribute__((ext_vector_type(8)));
typedef _Float16 half4 __attribute__((ext_vector_type(4)));
typedef float floatx4 __attribute__((ext_vector_type(4)));

static constexpr int BATCH = 1024;
static constexpr int NIN   = 512;    // in_features
static constexpr int MOUT  = 1024;   // out_features
static constexpr float LAMBD = 0.2f;
static constexpr float TOLF  = 1e-4f;
static constexpr int MAX_ITERS = 100;
static constexpr int MM = BATCH * MOUT;   // 1M elements

// Fragment-swizzled layout for 16x16x32 MFMA operands (A: rows, B: cols), f16:
//   flat = ((tile16*32 + kchunk32)*64 + lane)*8 + elem
//   lane = (idx&15) | (((k>>3)&3)<<4), elem = k&7
__device__ __forceinline__ size_t swz(int idx, int k) {
    return ((((size_t)(idx >> 4) * 32 + (k >> 5)) * 64 +
             ((idx & 15) | (((k >> 3) & 3) << 4))) << 3) + (k & 7);
}

__device__ __forceinline__ float shrinkf(float t) {
    float a = fabsf(t) - LAMBD;
    return a > 0.f ? copysignf(a, t) : 0.f;
}

// ---------------------------------------------------------------------------
// zero-init: t, enc, dec, swizzled enc halves, solved flags + tot
// ---------------------------------------------------------------------------
__global__ __launch_bounds__(256) void zero_init(float* t, float* enc,
                                                 float* dec, float* ench_f,
                                                 float* encl_f, int* solved) {
    int i = blockIdx.x * 256 + threadIdx.x;
    if (i < MM) { t[i] = 0.f; enc[i] = 0.f; }
    if (i < MM / 2) { dec[i] = 0.f; ench_f[i] = 0.f; encl_f[i] = 0.f; }
    if (i <= BATCH) solved[i] = 0;
}

// ---------------------------------------------------------------------------
// Th/Tl = B-fragment-swizzled split-f16 of Minv (col=n in 1024, k in 1024).
// ---------------------------------------------------------------------------
__global__ __launch_bounds__(256) void split_minv(const float* __restrict__ Minv,
                                                  _Float16* __restrict__ Th,
                                                  _Float16* __restrict__ Tl) {
    int g = blockIdx.x * 256 + threadIdx.x;   // 131072 threads
    int n = g & 1023, k0 = (g >> 10) << 3;
    half8 h, l;
    #pragma unroll
    for (int e = 0; e < 8; ++e) {
        float val = Minv[(size_t)(k0 + e) * MOUT + n];
        _Float16 hh = (_Float16)val;
        h[e] = hh;
        l[e] = (_Float16)(val - (float)hh);
    }
    size_t off = swz(n, k0);
    *(half8*)&Th[off] = h;
    *(half8*)&Tl[off] = l;
}

// ---------------------------------------------------------------------------
// wsh/wsl = B-fragment-swizzled split-f16 of weight (col=n in 512, k in 1024).
// ---------------------------------------------------------------------------
__global__ __launch_bounds__(256) void split_w(const float* __restrict__ w,
                                               _Float16* __restrict__ wsh,
                                               _Float16* __restrict__ wsl) {
    int g = blockIdx.x * 256 + threadIdx.x;   // 65536 threads
    int n = g & 511, k0 = (g >> 9) << 3;
    half8 h, l;
    #pragma unroll
    for (int e = 0; e < 8; ++e) {
        float val = w[(size_t)(k0 + e) * NIN + n];
        _Float16 hh = (_Float16)val;
        h[e] = hh;
        l[e] = (_Float16)(val - (float)hh);
    }
    size_t off = swz(n, k0);
    *(half8*)&wsh[off] = h;
    *(half8*)&wsl[off] = l;
}

// ---------------------------------------------------------------------------
// adb = x @ w^T (fp32, once). Epilogue emits beff0 = adb as A-swizzled h/l.
// ---------------------------------------------------------------------------
__global__ __launch_bounds__(256) void gemm_adb(const float* __restrict__ x,
                                                const float* __restrict__ w,
                                                float* __restrict__ adb,
                                                _Float16* __restrict__ bh,
                                                _Float16* __restrict__ bl) {
    __shared__ float As[16][68];
    __shared__ float Bs[16][68];
    const int tid = threadIdx.x;
    const int i0 = (blockIdx.x >> 4) * 64, j0 = (blockIdx.x & 15) * 64;
    const int tx = tid & 15, ty = tid >> 4;
    const int lr = tid >> 2, lk = (tid & 3) << 2;
    float acc[4][4] = {};
    for (int k0 = 0; k0 < NIN; k0 += 16) {
        float4 a4 = *(const float4*)&x[(i0 + lr) * NIN + k0 + lk];
        As[lk + 0][lr] = a4.x; As[lk + 1][lr] = a4.y;
        As[lk + 2][lr] = a4.z; As[lk + 3][lr] = a4.w;
        float4 b4 = *(const float4*)&w[(j0 + lr) * NIN + k0 + lk];
        Bs[lk + 0][lr] = b4.x; Bs[lk + 1][lr] = b4.y;
        Bs[lk + 2][lr] = b4.z; Bs[lk + 3][lr] = b4.w;
        __syncthreads();
        #pragma unroll
        for (int kk = 0; kk < 16; ++kk) {
            float4 a_ = *(const float4*)&As[kk][ty << 2];
            float4 b_ = *(const float4*)&Bs[kk][tx << 2];
            #pragma unroll
            for (int r = 0; r < 4; ++r) {
                float av = r == 0 ? a_.x : r == 1 ? a_.y : r == 2 ? a_.z : a_.w;
                acc[r][0] = fmaf(av, b_.x, acc[r][0]);
                acc[r][1] = fmaf(av, b_.y, acc[r][1]);
                acc[r][2] = fmaf(av, b_.z, acc[r][2]);
                acc[r][3] = fmaf(av, b_.w, acc[r][3]);
            }
        }
        __syncthreads();
    }
    const int k4 = j0 + (tx << 2);
    #pragma unroll
    for (int r = 0; r < 4; ++r) {
        const int row = i0 + (ty << 2) + r;
        *(float4*)&adb[(size_t)row * MOUT + k4] =
            make_float4(acc[r][0], acc[r][1], acc[r][2], acc[r][3]);
        half4 h, l;
        #pragma unroll
        for (int e = 0; e < 4; ++e) {
            _Float16 hh = (_Float16)acc[r][e];
            h[e] = hh;
            l[e] = (_Float16)(acc[r][e] - (float)hh);
        }
        size_t off = swz(row, k4);
        *(half4*)&bh[off] = h;
        *(half4*)&bl[off] = l;
    }
}

// ---------------------------------------------------------------------------
// One ADMM iteration, ONE dispatch, NO cross-block sync.
// Grid 256 = (mt 0..31 row-stripes of 32) x (nt 0..7 col-tiles of 128).
// bid&7 = nt -> XCD-aligned B slice (512 KB, L2-resident).
// Phases: [async A staging issued] -> prologue freeze-check(it-1) from
// normbuf plain stores -> barrier -> K=1024 barrier-free MFMA loop (A from
// LDS, B streamed global) -> Xk via LDS -> in-kernel row update (t-trick),
// beff written to parity-swapped bh/bl, per-nt norms stored for it.
// ---------------------------------------------------------------------------
__global__ __launch_bounds__(512, 1)
void admm_iter(const _Float16* __restrict__ bhr, const _Float16* __restrict__ blr,
               _Float16* __restrict__ bhw, _Float16* __restrict__ blw,
               const _Float16* __restrict__ Th, const _Float16* __restrict__ Tl,
               const float* __restrict__ adb, float* __restrict__ t,
               float* __restrict__ normbuf, int* solved,
               float* __restrict__ enc, _Float16* __restrict__ ench,
               _Float16* __restrict__ encl, int it) {
    __shared__ _Float16 Ash[128 * 512];   // 128 KB: chunk=((rt*32+kc)*2+hl)
    __shared__ float Xk[32 * 132];        // 16.9 KB (pad 132 -> benign banks)
    __shared__ int frozen[32];
    __shared__ int newf[32];

    int* tot = solved + BATCH;
    if (((volatile const int*)tot)[0] == BATCH) return;

    const int bid = blockIdx.x;
    const int mt = bid >> 3, nt = bid & 7;
    const int r0 = mt << 5, c0 = nt << 7;
    const int tid = threadIdx.x, lane = tid & 63, wv = tid >> 6;

    // ---- issue A staging early (async, hidden behind prologue)
    #pragma unroll
    for (int i = 0; i < 16; ++i) {
        const int ch = (wv << 4) + i;
        const int rt = ch >> 6, kc = (ch >> 1) & 31, hl = ch & 1;
        const _Float16* src = (hl ? blr : bhr) +
            ((((size_t)((mt << 1) + rt) * 32 + kc) << 9) + ((size_t)lane << 3));
        __builtin_amdgcn_global_load_lds(
            (const __attribute__((address_space(1))) void*)src,
            (__attribute__((address_space(3))) void*)&Ash[(size_t)ch << 9],
            16, 0, 0);
    }

    // ---- prologue: freeze-check for iteration it-1 (deterministic per block)
    if (tid < 256) {
        const int r = tid >> 3, ntp = tid & 7;
        const int row = r0 + r;
        const int sv = ((volatile const int*)solved)[row];
        float dx2 = 0.f, x2 = 0.f;
        if (it > 0 && !sv) {
            const float* nb = normbuf +
                (((((size_t)((it - 1) & 1) << 3) + ntp) << 10) + row) * 2;
            dx2 = nb[0];
            x2  = nb[1];
            #pragma unroll
            for (int o = 1; o < 8; o <<= 1) {
                dx2 += __shfl_xor(dx2, o);
                x2  += __shfl_xor(x2, o);
            }
        }
        if (ntp == 0) {
            const int nf = (it > 0 && !sv && dx2 < TOLF * TOLF * x2) ? 1 : 0;
            newf[r] = nf;
            frozen[r] = sv | nf;
        }
    }
    __syncthreads();   // prologue flags ready AND A staging drained

    // ---- newly-frozen rows: nt==0 writes enc + swizzled enc + solved + tot
    if (nt == 0) {
        for (int r = 0; r < 32; ++r) {
            if (!newf[r]) continue;
            const int row = r0 + r;
            const int col = tid << 1;
            float2 tv = *(const float2*)&t[((size_t)row << 10) + col];
            float v0 = shrinkf(tv.x), v1 = shrinkf(tv.y);
            *(float2*)&enc[((size_t)row << 10) + col] = make_float2(v0, v1);
            {
                _Float16 h0 = (_Float16)v0;
                ench[swz(row, col)] = h0;
                encl[swz(row, col)] = (_Float16)(v0 - (float)h0);
                _Float16 h1 = (_Float16)v1;
                ench[swz(row, col + 1)] = h1;
                encl[swz(row, col + 1)] = (_Float16)(v1 - (float)h1);
            }
            if (tid == 0) {
                ((volatile int*)solved)[row] = 1;
                atomicAdd(tot, 1);
            }
        }
    }
    int fcnt = 0;
    #pragma unroll
    for (int r = 0; r < 32; ++r) fcnt += frozen[r];
    if (fcnt == 32) return;                  // whole 32-row stripe frozen

    // ---- GEMM: 32 rows x 128 cols, K = 1024, barrier-free
    const int wm = wv >> 2, wn = wv & 3;     // wave = 16 rows x 32 cols
    const int ct0 = (nt << 3) + (wn << 1);   // first of 2 global col-tiles
    const _Float16* pBh = Th + (((size_t)ct0 << 14) + ((size_t)lane << 3));
    const _Float16* pBl = Tl + (((size_t)ct0 << 14) + ((size_t)lane << 3));

    floatx4 acc[2] = {};
    #pragma unroll 4
    for (int kc = 0; kc < 32; ++kc) {
        half8 ah = *(const half8*)&Ash[((((wm << 5) + kc) << 10)) + (lane << 3)];
        half8 al = *(const half8*)&Ash[((((wm << 5) + kc) << 10) | 512) + (lane << 3)];
        #pragma unroll
        for (int j = 0; j < 2; ++j) {
            half8 fh = *(const half8*)(pBh + ((size_t)j << 14) + ((size_t)kc << 9));
            half8 fl = *(const half8*)(pBl + ((size_t)j << 14) + ((size_t)kc << 9));
            acc[j] = __builtin_amdgcn_mfma_f32_16x16x32_f16(ah, fl, acc[j], 0, 0, 0);
            acc[j] = __builtin_amdgcn_mfma_f32_16x16x32_f16(al, fh, acc[j], 0, 0, 0);
            acc[j] = __builtin_amdgcn_mfma_f32_16x16x32_f16(ah, fh, acc[j], 0, 0, 0);
        }
    }

    // scatter C to Xk: col = lane&15, row = (lane>>4)*4 + r  [m89 verified]
    {
        const int crow = (wm << 4) + ((lane >> 4) << 2);
        const int ccol = (wn << 5) + (lane & 15);
        #pragma unroll
        for (int j = 0; j < 2; ++j)
            #pragma unroll
            for (int r = 0; r < 4; ++r)
                Xk[(crow + r) * 132 + ccol + (j << 4)] = acc[j][r];
    }
    __syncthreads();

    // ---- update: thread = (row ur, col-octet uk); t-trick, ref-order math
    const int ur = tid >> 4;
    const int uk = (tid & 15) << 3;
    if (!frozen[ur]) {
        const int row = r0 + ur;
        const int gk = c0 + uk;
        const size_t gj = ((size_t)row << 10) + gk;
        float4 xa = *(const float4*)&Xk[ur * 132 + uk];
        float4 xb = *(const float4*)&Xk[ur * 132 + uk + 4];
        float4 t0 = *(const float4*)&t[gj];
        float4 t1 = *(const float4*)&t[gj + 4];
        float4 a0 = *(const float4*)&adb[gj];
        float4 a1 = *(const float4*)&adb[gj + 4];
        float xv[8] = {xa.x, xa.y, xa.z, xa.w, xb.x, xb.y, xb.z, xb.w};
        float tp[8] = {t0.x, t0.y, t0.z, t0.w, t1.x, t1.y, t1.z, t1.w};
        float ap[8] = {a0.x, a0.y, a0.z, a0.w, a1.x, a1.y, a1.z, a1.w};
        float tn[8];
        half8 hb, lb;
        float dx2 = 0.f, x2 = 0.f;
        #pragma unroll
        for (int e = 0; e < 8; ++e) {
            float vprev = shrinkf(tp[e]);
            float uu = tp[e] - vprev;        // u_prev (bitwise = stored u)
            float tnn = xv[e] + uu;          // xk + u (ref order)
            float vv = shrinkf(tnn);
            float un = tnn - vv;             // u_new
            float d = vv - vprev;
            dx2 += d * d;
            x2 += vv * vv;
            tn[e] = tnn;
            float nb = (ap[e] + vv) - un;    // (adb + v_new) - u_new
            _Float16 hh = (_Float16)nb;
            hb[e] = hh;
            lb[e] = (_Float16)(nb - (float)hh);
        }
        *(float4*)&t[gj]     = make_float4(tn[0], tn[1], tn[2], tn[3]);
        *(float4*)&t[gj + 4] = make_float4(tn[4], tn[5], tn[6], tn[7]);
        const size_t so = swz(row, gk);      // octet-contiguous
        *(half8*)&bhw[so] = hb;
        *(half8*)&blw[so] = lb;
        #pragma unroll
        for (int o = 1; o < 16; o <<= 1) {
            dx2 += __shfl_xor(dx2, o);
            x2  += __shfl_xor(x2, o);
        }
        if ((tid & 15) == 0) {
            float* nb = normbuf +
                (((((size_t)(it & 1) << 3) + nt) << 10) + row) * 2;
            nb[0] = dx2;
            nb[1] = x2;
        }
    }
}

// ---------------------------------------------------------------------------
// finalize: apply the freeze-check for the last iteration's norms.
// ---------------------------------------------------------------------------
__global__ __launch_bounds__(256) void finalize(const float* __restrict__ nb,
                                                const float* __restrict__ t,
                                                const int* __restrict__ solved,
                                                float* __restrict__ enc,
                                                _Float16* __restrict__ ench,
                                                _Float16* __restrict__ encl) {
    const int row = blockIdx.x;
    if (solved[row]) return;
    __shared__ int conv;
    if (threadIdx.x == 0) {
        float dx2 = 0.f, x2 = 0.f;
        for (int p = 0; p < 8; ++p) {
            dx2 += nb[((((size_t)p) << 10) + row) * 2 + 0];
            x2  += nb[((((size_t)p) << 10) + row) * 2 + 1];
        }
        conv = (dx2 < TOLF * TOLF * x2) ? 1 : 0;
    }
    __syncthreads();
    if (!conv) return;
    const int c4 = threadIdx.x << 2;
    float4 tv = *(const float4*)&t[((size_t)row << 10) + c4];
    float v[4] = {shrinkf(tv.x), shrinkf(tv.y), shrinkf(tv.z), shrinkf(tv.w)};
    *(float4*)&enc[((size_t)row << 10) + c4] = make_float4(v[0], v[1], v[2], v[3]);
    half4 h, l;
    #pragma unroll
    for (int e = 0; e < 4; ++e) {
        _Float16 hh = (_Float16)v[e];
        h[e] = hh;
        l[e] = (_Float16)(v[e] - (float)hh);
    }
    const size_t so = swz(row, c4);
    *(half4*)&ench[so] = h;
    *(half4*)&encl[so] = l;
}

// ---------------------------------------------------------------------------
// dec = enc @ w, split-f16 MFMA, runs ONCE. 128x128 tile, S=8 whole-partition
// A staging (64 KB), one barrier, atomicAdd epilogue (one-time cost).
// ---------------------------------------------------------------------------
__global__ __launch_bounds__(256, 2)
void mfma_dec(const _Float16* __restrict__ Ahg, const _Float16* __restrict__ Alg,
              const _Float16* __restrict__ Bhg, const _Float16* __restrict__ Blg,
              float* __restrict__ out) {
    constexpr int NSTR = NIN;              // 512
    constexpr int NT = NSTR / 128;         // 4
    const int bid = blockIdx.x;
    const int c = bid & 7, t = bid >> 3;
    const int mt = t / NT, nt = t % NT;
    const int tid = threadIdx.x, lane = tid & 63;

    __shared__ _Float16 Ash[64 * 512];     // 64 KB

    const int wv = tid >> 6;
    const int wm = (tid >> 7) & 1, wn = (tid >> 6) & 1;
    const int kf0 = c << 2;

    #pragma unroll
    for (int i = 0; i < 16; ++i) {
        const int chunk = (wv << 4) + i;
        const int rt = chunk >> 3, kc = (chunk >> 1) & 3, hl = chunk & 1;
        const _Float16* src = (hl ? Alg : Ahg) +
            ((((size_t)((mt << 3) + rt) * 32 + kf0 + kc) << 9) + ((size_t)lane << 3));
        __builtin_amdgcn_global_load_lds(
            (const __attribute__((address_space(1))) void*)src,
            (__attribute__((address_space(3))) void*)&Ash[(size_t)chunk << 9],
            16, 0, 0);
    }
    __syncthreads();

    const int ct0 = nt * 8 + (wn << 2);
    const _Float16* pBh = Bhg + ((((size_t)ct0 * 32 + kf0) * 64 + lane) << 3);
    const _Float16* pBl = Blg + ((((size_t)ct0 * 32 + kf0) * 64 + lane) << 3);

    floatx4 acc[4][4] = {};
    #pragma unroll
    for (int s = 0; s < 4; ++s) {
        half8 bhf[4], blf[4];
        #pragma unroll
        for (int j = 0; j < 4; ++j) {
            bhf[j] = *(const half8*)(pBh + ((size_t)j << 14) + ((size_t)s << 9));
            blf[j] = *(const half8*)(pBl + ((size_t)j << 14) + ((size_t)s << 9));
        }
        half8 ah[4], al[4];
        #pragma unroll
        for (int i = 0; i < 4; ++i) {
            const int rt = (wm << 2) + i;
            ah[i] = *(const half8*)&Ash[((((rt << 2) + s) << 1) << 9) + (lane << 3)];
            al[i] = *(const half8*)&Ash[(((((rt << 2) + s) << 1) + 1) << 9) + (lane << 3)];
        }
        #pragma unroll
        for (int i = 0; i < 4; ++i)
            #pragma unroll
            for (int j = 0; j < 4; ++j) {
                acc[i][j] = __builtin_amdgcn_mfma_f32_16x16x32_f16(
                    ah[i], blf[j], acc[i][j], 0, 0, 0);
                acc[i][j] = __builtin_amdgcn_mfma_f32_16x16x32_f16(
                    al[i], bhf[j], acc[i][j], 0, 0, 0);
                acc[i][j] = __builtin_amdgcn_mfma_f32_16x16x32_f16(
                    ah[i], bhf[j], acc[i][j], 0, 0, 0);
            }
    }

    const int orow = (lane >> 4) << 2;
    #pragma unroll
    for (int i = 0; i < 4; ++i) {
        const int gr = (mt << 7) + (wm << 6) + (i << 4) + orow;
        #pragma unroll
        for (int j = 0; j < 4; ++j) {
            const int gc = nt * 128 + (wn << 6) + (j << 4) + (lane & 15);
            #pragma unroll
            for (int r = 0; r < 4; ++r)
                atomicAdd(&out[(size_t)(gr + r) * NSTR + gc], acc[i][j][r]);
        }
    }
}

// ---------------------------------------------------------------------------
extern "C" void kernel_launch(void* const* d_in, const int* in_sizes, int n_in,
                              void* d_out, int out_size, void* d_ws, size_t ws_size,
                              hipStream_t stream) {
    const float* x    = (const float*)d_in[0];
    const float* w    = (const float*)d_in[1];
    const float* Minv = (const float*)d_in[2];

    float* enc = (float*)d_out;          // encoded: 1024*1024
    float* dec = enc + MM;               // decoded: 1024*512

    // ws (floats): adb MM | t MM | normbuf 2*8*1024*2 | halves: bh0,bl0,bh1,
    // bl1,Th,Tl,ench,encl MM each, wsh,wsl MM/2 | solved+tot. ~26 MB.
    float* ws      = (float*)d_ws;
    float* adb     = ws;
    float* t       = ws + (size_t)MM;
    float* normbuf = ws + 2 * (size_t)MM;

    _Float16* bh0  = (_Float16*)(normbuf + 2 * 8 * 1024 * 2);
    _Float16* bl0  = bh0 + (size_t)MM;
    _Float16* bh1  = bl0 + (size_t)MM;
    _Float16* bl1  = bh1 + (size_t)MM;
    _Float16* Th   = bl1 + (size_t)MM;
    _Float16* Tl   = Th + (size_t)MM;
    _Float16* ench = Tl + (size_t)MM;
    _Float16* encl = ench + (size_t)MM;
    _Float16* wsh  = encl + (size_t)MM;
    _Float16* wsl  = wsh + (size_t)(NIN * MOUT);
    int* solved    = (int*)(wsl + (size_t)(NIN * MOUT));

    zero_init<<<(MM + 255) / 256, 256, 0, stream>>>(t, enc, dec, (float*)ench,
                                                    (float*)encl, solved);
    split_minv<<<512, 256, 0, stream>>>(Minv, Th, Tl);
    split_w<<<256, 256, 0, stream>>>(w, wsh, wsl);
    gemm_adb<<<256, 256, 0, stream>>>(x, w, adb, bh0, bl0);

    for (int it = 0; it < MAX_ITERS; ++it) {
        const int p = it & 1;
        admm_iter<<<256, 512, 0, stream>>>(
            p ? bh1 : bh0, p ? bl1 : bl0,      // read buffer (parity)
            p ? bh0 : bh1, p ? bl0 : bl1,      // write buffer
            Th, Tl, adb, t, normbuf, solved, enc, ench, encl, it);
    }

    finalize<<<BATCH, 256, 0, stream>>>(
        normbuf + (size_t)((MAX_ITERS - 1) & 1) * 8 * 1024 * 2, t, solved, enc,
        ench, encl);

    mfma_dec<<<256, 256, 0, stream>>>(ench, encl, wsh, wsl, dec);
}